// Round 3
// baseline (153.182 us; speedup 1.0000x reference)
//
#include <hip/hip_runtime.h>
#include <cfloat>

// DMBERT candidate-span max-pool + classifier head, fused.
// hidden: [B=32, S=512, H=1024] f32
// W: [2H=2048, 34] f32, b: [34] f32
// cand_batch/cand_cut: [N=256] i32
// out: [N, 34] f32
//
// One block per candidate. Thread t owns columns 4t..4t+3 (float4).
// cut is block-uniform -> two branchless loops (left max / right max).
// Epilogue GEMM done from an 8KB LDS pooled buffer: 4 waves split k,
// lanes 0..33 each own a label, LDS partial reduce + bias.

constexpr int S_LEN = 512;
constexpr int HDIM  = 1024;
constexpr int NLAB  = 34;

__global__ __launch_bounds__(256) void dmbert_pool_gemm(
    const float* __restrict__ hidden,
    const float* __restrict__ W,
    const float* __restrict__ bias,
    const int*   __restrict__ cand_batch,
    const int*   __restrict__ cand_cut,
    float*       __restrict__ out)
{
    __shared__ float pooled[2 * HDIM];      // [L(1024) | R(1024)]
    __shared__ float partial[4][NLAB];

    const int n   = blockIdx.x;
    const int t   = threadIdx.x;
    const int bi  = cand_batch[n];
    const int cut = cand_cut[n];            // block-uniform

    const float* base = hidden + (size_t)bi * S_LEN * HDIM + 4 * t;

    float4 mL = make_float4(-FLT_MAX, -FLT_MAX, -FLT_MAX, -FLT_MAX);
    float4 mR = mL;

    // left segment: s in [0, cut)
    #pragma unroll 4
    for (int s = 0; s < cut; ++s) {
        float4 v = *reinterpret_cast<const float4*>(base + (size_t)s * HDIM);
        mL.x = fmaxf(mL.x, v.x);
        mL.y = fmaxf(mL.y, v.y);
        mL.z = fmaxf(mL.z, v.z);
        mL.w = fmaxf(mL.w, v.w);
    }
    // right segment: s in [cut, S)
    #pragma unroll 4
    for (int s = cut; s < S_LEN; ++s) {
        float4 v = *reinterpret_cast<const float4*>(base + (size_t)s * HDIM);
        mR.x = fmaxf(mR.x, v.x);
        mR.y = fmaxf(mR.y, v.y);
        mR.z = fmaxf(mR.z, v.z);
        mR.w = fmaxf(mR.w, v.w);
    }

    *reinterpret_cast<float4*>(&pooled[4 * t])        = mL;
    *reinterpret_cast<float4*>(&pooled[HDIM + 4 * t]) = mR;
    __syncthreads();

    // GEMM epilogue: pooled[2048] @ W[2048,34] + b
    const int w    = t >> 6;      // wave id 0..3, owns k in [512w, 512w+512)
    const int lane = t & 63;
    if (lane < NLAB) {
        const int k0 = w * (2 * HDIM / 4);
        float acc = 0.0f;
        #pragma unroll 8
        for (int k = k0; k < k0 + (2 * HDIM / 4); ++k) {
            acc = fmaf(pooled[k], W[(size_t)k * NLAB + lane], acc);
        }
        partial[w][lane] = acc;
    }
    __syncthreads();

    if (t < NLAB) {
        out[(size_t)n * NLAB + t] =
            partial[0][t] + partial[1][t] + partial[2][t] + partial[3][t] + bias[t];
    }
}

extern "C" void kernel_launch(void* const* d_in, const int* in_sizes, int n_in,
                              void* d_out, int out_size, void* d_ws, size_t ws_size,
                              hipStream_t stream) {
    const float* hidden = (const float*)d_in[0];
    const float* W      = (const float*)d_in[1];
    const float* bias   = (const float*)d_in[2];
    const int*   cb     = (const int*)d_in[3];
    const int*   cc     = (const int*)d_in[4];
    float*       outp   = (float*)d_out;

    const int ncand = in_sizes[3];  // 256
    dmbert_pool_gemm<<<ncand, 256, 0, stream>>>(hidden, W, bias, cb, cc, outp);
}

// Round 4
// 119.841 us; speedup vs baseline: 1.2782x; 1.2782x over previous
//
#include <hip/hip_runtime.h>
#include <cfloat>

// DMBERT candidate-span max-pool + classifier head.
// hidden: [B=32, S=512, H=1024] f32; W: [2048,34]; b:[34]
// cand_batch/cand_cut: [N=256] i32 ; out: [N,34] f32
//
// Two-phase: (1) per-(row,chunk) column-max into ws — reads hidden exactly
// once, fully parallel (grid B*NCHUNK=1024). (2) per-candidate: combine
// full chunks from ws + boundary token rows from hidden (<=CHUNK rows each
// side), then fused GEMM epilogue. Cuts logical traffic 512MB -> ~110MB.

constexpr int S_LEN  = 512;
constexpr int HDIM   = 1024;
constexpr int NLAB   = 34;
constexpr int CHUNK  = 16;
constexpr int NCHUNK = S_LEN / CHUNK;   // 32

__device__ __forceinline__ void fmax4(float4& a, const float4 v) {
    a.x = fmaxf(a.x, v.x); a.y = fmaxf(a.y, v.y);
    a.z = fmaxf(a.z, v.z); a.w = fmaxf(a.w, v.w);
}

// ---- Kernel 1: chunkmax[b][c][h] = max over tokens [c*CHUNK, (c+1)*CHUNK)
__global__ __launch_bounds__(256) void chunkmax_kernel(
    const float* __restrict__ hidden, float* __restrict__ ws)
{
    const int blk = blockIdx.x;           // b * NCHUNK + c
    const int b   = blk / NCHUNK;
    const int c   = blk % NCHUNK;
    const int t   = threadIdx.x;          // owns cols 4t..4t+3

    const float* base = hidden + ((size_t)b * S_LEN + (size_t)c * CHUNK) * HDIM + 4 * t;
    float4 m = make_float4(-FLT_MAX, -FLT_MAX, -FLT_MAX, -FLT_MAX);
    #pragma unroll
    for (int s = 0; s < CHUNK; ++s)
        fmax4(m, *reinterpret_cast<const float4*>(base + (size_t)s * HDIM));

    *reinterpret_cast<float4*>(ws + ((size_t)b * NCHUNK + c) * HDIM + 4 * t) = m;
}

// ---- Kernel 2: per-candidate pooling from ws + boundary rows, then GEMM.
__global__ __launch_bounds__(256) void pool_gemm_kernel(
    const float* __restrict__ hidden,
    const float* __restrict__ ws,
    const float* __restrict__ W,
    const float* __restrict__ bias,
    const int*   __restrict__ cand_batch,
    const int*   __restrict__ cand_cut,
    float*       __restrict__ out)
{
    __shared__ float pooled[2 * HDIM];
    __shared__ float partial[4][NLAB];

    const int n   = blockIdx.x;
    const int t   = threadIdx.x;
    const int b   = cand_batch[n];
    const int cut = cand_cut[n];                      // block-uniform
    const int fcL = cut / CHUNK;                      // full chunks 0..fcL-1 -> left
    const int fcR = (cut + CHUNK - 1) / CHUNK;        // full chunks fcR..NCHUNK-1 -> right

    const float* hbase  = hidden + (size_t)b * S_LEN * HDIM + 4 * t;
    const float* wsbase = ws + (size_t)b * NCHUNK * HDIM + 4 * t;

    float4 mL = make_float4(-FLT_MAX, -FLT_MAX, -FLT_MAX, -FLT_MAX);
    float4 mR = mL;

    #pragma unroll 4
    for (int c = 0; c < fcL; ++c)
        fmax4(mL, *reinterpret_cast<const float4*>(wsbase + (size_t)c * HDIM));
    #pragma unroll 4
    for (int s = fcL * CHUNK; s < cut; ++s)
        fmax4(mL, *reinterpret_cast<const float4*>(hbase + (size_t)s * HDIM));

    #pragma unroll 4
    for (int s = cut; s < fcR * CHUNK; ++s)
        fmax4(mR, *reinterpret_cast<const float4*>(hbase + (size_t)s * HDIM));
    #pragma unroll 4
    for (int c = fcR; c < NCHUNK; ++c)
        fmax4(mR, *reinterpret_cast<const float4*>(wsbase + (size_t)c * HDIM));

    *reinterpret_cast<float4*>(&pooled[4 * t])        = mL;
    *reinterpret_cast<float4*>(&pooled[HDIM + 4 * t]) = mR;
    __syncthreads();

    const int w    = t >> 6;          // wave 0..3 owns k in [512w, 512w+512)
    const int lane = t & 63;
    if (lane < NLAB) {
        const int k0 = w * (2 * HDIM / 4);
        float acc = 0.0f;
        #pragma unroll 8
        for (int k = k0; k < k0 + (2 * HDIM / 4); ++k)
            acc = fmaf(pooled[k], W[(size_t)k * NLAB + lane], acc);
        partial[w][lane] = acc;
    }
    __syncthreads();

    if (t < NLAB) {
        out[(size_t)n * NLAB + t] =
            partial[0][t] + partial[1][t] + partial[2][t] + partial[3][t] + bias[t];
    }
}

// ---- Fallback: proven single-kernel path (used only if ws too small).
__global__ __launch_bounds__(256) void dmbert_pool_gemm(
    const float* __restrict__ hidden,
    const float* __restrict__ W,
    const float* __restrict__ bias,
    const int*   __restrict__ cand_batch,
    const int*   __restrict__ cand_cut,
    float*       __restrict__ out)
{
    __shared__ float pooled[2 * HDIM];
    __shared__ float partial[4][NLAB];

    const int n   = blockIdx.x;
    const int t   = threadIdx.x;
    const int bi  = cand_batch[n];
    const int cut = cand_cut[n];

    const float* base = hidden + (size_t)bi * S_LEN * HDIM + 4 * t;
    float4 mL = make_float4(-FLT_MAX, -FLT_MAX, -FLT_MAX, -FLT_MAX);
    float4 mR = mL;

    #pragma unroll 4
    for (int s = 0; s < cut; ++s)
        fmax4(mL, *reinterpret_cast<const float4*>(base + (size_t)s * HDIM));
    #pragma unroll 4
    for (int s = cut; s < S_LEN; ++s)
        fmax4(mR, *reinterpret_cast<const float4*>(base + (size_t)s * HDIM));

    *reinterpret_cast<float4*>(&pooled[4 * t])        = mL;
    *reinterpret_cast<float4*>(&pooled[HDIM + 4 * t]) = mR;
    __syncthreads();

    const int w    = t >> 6;
    const int lane = t & 63;
    if (lane < NLAB) {
        const int k0 = w * (2 * HDIM / 4);
        float acc = 0.0f;
        #pragma unroll 8
        for (int k = k0; k < k0 + (2 * HDIM / 4); ++k)
            acc = fmaf(pooled[k], W[(size_t)k * NLAB + lane], acc);
        partial[w][lane] = acc;
    }
    __syncthreads();

    if (t < NLAB) {
        out[(size_t)n * NLAB + t] =
            partial[0][t] + partial[1][t] + partial[2][t] + partial[3][t] + bias[t];
    }
}

extern "C" void kernel_launch(void* const* d_in, const int* in_sizes, int n_in,
                              void* d_out, int out_size, void* d_ws, size_t ws_size,
                              hipStream_t stream) {
    const float* hidden = (const float*)d_in[0];
    const float* W      = (const float*)d_in[1];
    const float* bias   = (const float*)d_in[2];
    const int*   cb     = (const int*)d_in[3];
    const int*   cc     = (const int*)d_in[4];
    float*       outp   = (float*)d_out;

    const int ncand = in_sizes[3];                       // 256
    const int B     = in_sizes[0] / (S_LEN * HDIM);      // 32
    const size_t ws_needed = (size_t)B * NCHUNK * HDIM * sizeof(float);  // 4 MB

    if (ws_size >= ws_needed) {
        float* chunkmax = (float*)d_ws;
        chunkmax_kernel<<<B * NCHUNK, 256, 0, stream>>>(hidden, chunkmax);
        pool_gemm_kernel<<<ncand, 256, 0, stream>>>(hidden, chunkmax, W, bias, cb, cc, outp);
    } else {
        dmbert_pool_gemm<<<ncand, 256, 0, stream>>>(hidden, W, bias, cb, cc, outp);
    }
}

// Round 5
// 116.706 us; speedup vs baseline: 1.3125x; 1.0269x over previous
//
#include <hip/hip_runtime.h>
#include <cfloat>

// DMBERT candidate-span max-pool + classifier head. 3-kernel pipeline:
//  K1 chunkmax: ws0[b][c][h] = max over 16-token chunk  (reads hidden once)
//  K2 pool:     per (candidate, col-quarter) combine full chunks + boundary
//               rows -> pooled[n][2048] in ws   (1024 one-wave blocks)
//  K3 gemm:     pooled[n] @ W + b -> out        (256 blocks, k split 4 ways)
// hidden: [B=32, S=512, H=1024] f32; W: [2048,34]; b:[34]
// cand_batch/cand_cut: [N=256] i32 ; out: [N,34] f32

constexpr int S_LEN  = 512;
constexpr int HDIM   = 1024;
constexpr int NLAB   = 34;
constexpr int CHUNK  = 16;
constexpr int NCHUNK = S_LEN / CHUNK;   // 32

__device__ __forceinline__ void fmax4(float4& a, const float4 v) {
    a.x = fmaxf(a.x, v.x); a.y = fmaxf(a.y, v.y);
    a.z = fmaxf(a.z, v.z); a.w = fmaxf(a.w, v.w);
}

// ---- K1: chunkmax[b][c][h] = max over tokens [c*CHUNK, (c+1)*CHUNK)
__global__ __launch_bounds__(256) void chunkmax_kernel(
    const float* __restrict__ hidden, float* __restrict__ ws0)
{
    const int blk = blockIdx.x;           // b * NCHUNK + c
    const int b   = blk / NCHUNK;
    const int c   = blk % NCHUNK;
    const int t   = threadIdx.x;          // owns cols 4t..4t+3

    const float* base = hidden + ((size_t)b * S_LEN + (size_t)c * CHUNK) * HDIM + 4 * t;
    float4 m = make_float4(-FLT_MAX, -FLT_MAX, -FLT_MAX, -FLT_MAX);
    #pragma unroll
    for (int s = 0; s < CHUNK; ++s)
        fmax4(m, *reinterpret_cast<const float4*>(base + (size_t)s * HDIM));

    *reinterpret_cast<float4*>(ws0 + ((size_t)b * NCHUNK + c) * HDIM + 4 * t) = m;
}

// ---- K2: pooled[n][0:1024]=L-max, [1024:2048]=R-max; one wave per
//          (candidate, 256-col quarter). All loads independent -> pipelined.
__global__ __launch_bounds__(64) void pool_kernel(
    const float* __restrict__ hidden,
    const float* __restrict__ ws0,
    const int*   __restrict__ cand_batch,
    const int*   __restrict__ cand_cut,
    float*       __restrict__ pooled)
{
    const int n   = blockIdx.x;
    const int q   = blockIdx.y;                       // col quarter 0..3
    const int t   = threadIdx.x;                      // owns 4 cols
    const int col = q * 256 + 4 * t;
    const int b   = cand_batch[n];
    const int cut = cand_cut[n];                      // block-uniform
    const int fcL = cut / CHUNK;                      // chunks 0..fcL-1 fully left
    const int fcR = (cut + CHUNK - 1) / CHUNK;        // chunks fcR.. fully right

    const float* hbase = hidden + (size_t)b * S_LEN * HDIM + col;
    const float* wbase = ws0 + (size_t)b * NCHUNK * HDIM + col;

    float4 mL = make_float4(-FLT_MAX, -FLT_MAX, -FLT_MAX, -FLT_MAX);
    float4 mR = mL;

    #pragma unroll 4
    for (int c = 0; c < fcL; ++c)
        fmax4(mL, *reinterpret_cast<const float4*>(wbase + (size_t)c * HDIM));
    #pragma unroll 4
    for (int s = fcL * CHUNK; s < cut; ++s)
        fmax4(mL, *reinterpret_cast<const float4*>(hbase + (size_t)s * HDIM));

    #pragma unroll 4
    for (int s = cut; s < fcR * CHUNK; ++s)
        fmax4(mR, *reinterpret_cast<const float4*>(hbase + (size_t)s * HDIM));
    #pragma unroll 4
    for (int c = fcR; c < NCHUNK; ++c)
        fmax4(mR, *reinterpret_cast<const float4*>(wbase + (size_t)c * HDIM));

    float* prow = pooled + (size_t)n * (2 * HDIM);
    *reinterpret_cast<float4*>(prow + col)        = mL;
    *reinterpret_cast<float4*>(prow + HDIM + col) = mR;
}

// ---- K3: out[n][l] = pooled[n] @ W[:,l] + b[l]; wave w owns k-slice.
__global__ __launch_bounds__(256) void gemm_kernel(
    const float* __restrict__ pooled,
    const float* __restrict__ W,
    const float* __restrict__ bias,
    float*       __restrict__ out)
{
    __shared__ float partial[4][NLAB];

    const int n    = blockIdx.x;
    const int t    = threadIdx.x;
    const int w    = t >> 6;          // wave 0..3 -> k in [512w, 512w+512)
    const int lane = t & 63;

    if (lane < NLAB) {
        const int k0 = w * 512;
        const float4* p4 = reinterpret_cast<const float4*>(
            pooled + (size_t)n * (2 * HDIM) + k0);
        float acc = 0.0f;
        #pragma unroll 4
        for (int kk = 0; kk < 128; ++kk) {
            const float4 pv = p4[kk];
            const int k = k0 + 4 * kk;
            acc = fmaf(pv.x, W[(size_t)(k + 0) * NLAB + lane], acc);
            acc = fmaf(pv.y, W[(size_t)(k + 1) * NLAB + lane], acc);
            acc = fmaf(pv.z, W[(size_t)(k + 2) * NLAB + lane], acc);
            acc = fmaf(pv.w, W[(size_t)(k + 3) * NLAB + lane], acc);
        }
        partial[w][lane] = acc;
    }
    __syncthreads();

    if (t < NLAB) {
        out[(size_t)n * NLAB + t] =
            partial[0][t] + partial[1][t] + partial[2][t] + partial[3][t] + bias[t];
    }
}

// ---- Fallback: proven single-kernel path (only if ws too small).
__global__ __launch_bounds__(256) void dmbert_pool_gemm(
    const float* __restrict__ hidden,
    const float* __restrict__ W,
    const float* __restrict__ bias,
    const int*   __restrict__ cand_batch,
    const int*   __restrict__ cand_cut,
    float*       __restrict__ out)
{
    __shared__ float pooled[2 * HDIM];
    __shared__ float partial[4][NLAB];

    const int n   = blockIdx.x;
    const int t   = threadIdx.x;
    const int bi  = cand_batch[n];
    const int cut = cand_cut[n];

    const float* base = hidden + (size_t)bi * S_LEN * HDIM + 4 * t;
    float4 mL = make_float4(-FLT_MAX, -FLT_MAX, -FLT_MAX, -FLT_MAX);
    float4 mR = mL;

    #pragma unroll 4
    for (int s = 0; s < cut; ++s)
        fmax4(mL, *reinterpret_cast<const float4*>(base + (size_t)s * HDIM));
    #pragma unroll 4
    for (int s = cut; s < S_LEN; ++s)
        fmax4(mR, *reinterpret_cast<const float4*>(base + (size_t)s * HDIM));

    *reinterpret_cast<float4*>(&pooled[4 * t])        = mL;
    *reinterpret_cast<float4*>(&pooled[HDIM + 4 * t]) = mR;
    __syncthreads();

    const int w    = t >> 6;
    const int lane = t & 63;
    if (lane < NLAB) {
        const int k0 = w * (2 * HDIM / 4);
        float acc = 0.0f;
        #pragma unroll 8
        for (int k = k0; k < k0 + (2 * HDIM / 4); ++k)
            acc = fmaf(pooled[k], W[(size_t)k * NLAB + lane], acc);
        partial[w][lane] = acc;
    }
    __syncthreads();

    if (t < NLAB) {
        out[(size_t)n * NLAB + t] =
            partial[0][t] + partial[1][t] + partial[2][t] + partial[3][t] + bias[t];
    }
}

extern "C" void kernel_launch(void* const* d_in, const int* in_sizes, int n_in,
                              void* d_out, int out_size, void* d_ws, size_t ws_size,
                              hipStream_t stream) {
    const float* hidden = (const float*)d_in[0];
    const float* W      = (const float*)d_in[1];
    const float* bias   = (const float*)d_in[2];
    const int*   cb     = (const int*)d_in[3];
    const int*   cc     = (const int*)d_in[4];
    float*       outp   = (float*)d_out;

    const int ncand = in_sizes[3];                       // 256
    const int B     = in_sizes[0] / (S_LEN * HDIM);      // 32
    const size_t cm_elems = (size_t)B * NCHUNK * HDIM;           // 1M floats (4MB)
    const size_t ws_needed = (cm_elems + (size_t)ncand * 2 * HDIM) * sizeof(float);

    if (ws_size >= ws_needed) {
        float* cm     = (float*)d_ws;
        float* pooled = cm + cm_elems;
        chunkmax_kernel<<<B * NCHUNK, 256, 0, stream>>>(hidden, cm);
        pool_kernel<<<dim3(ncand, 4), 64, 0, stream>>>(hidden, cm, cb, cc, pooled);
        gemm_kernel<<<ncand, 256, 0, stream>>>(pooled, W, bias, outp);
    } else {
        dmbert_pool_gemm<<<ncand, 256, 0, stream>>>(hidden, W, bias, cb, cc, outp);
    }
}

// Round 6
// 107.538 us; speedup vs baseline: 1.4244x; 1.0853x over previous
//
#include <hip/hip_runtime.h>
#include <cfloat>

// DMBERT candidate-span max-pool + classifier head. 2-kernel pipeline:
//  K1 chunkmax:  ws0[b][c][h] = col-max over 16-token chunk (reads hidden once)
//  K2 pool_gemm2: per candidate, 1024 threads = 4 row-teams x 256 cols.
//     Team g covers chunks c%4==g and boundary rows s%4==g -> ~16 loads/thread
//     (vs 62 single-team), LDS 4-way combine, then 16-wave GEMM epilogue.
// hidden: [B=32, S=512, H=1024] f32; W: [2048,34]; b:[34]
// cand_batch/cand_cut: [N=256] i32 ; out: [N,34] f32

constexpr int S_LEN  = 512;
constexpr int HDIM   = 1024;
constexpr int NLAB   = 34;
constexpr int CHUNK  = 16;
constexpr int NCHUNK = S_LEN / CHUNK;   // 32

__device__ __forceinline__ void fmax4(float4& a, const float4 v) {
    a.x = fmaxf(a.x, v.x); a.y = fmaxf(a.y, v.y);
    a.z = fmaxf(a.z, v.z); a.w = fmaxf(a.w, v.w);
}

// ---- K1: chunkmax[b][c][h] = max over tokens [c*CHUNK, (c+1)*CHUNK)
__global__ __launch_bounds__(256) void chunkmax_kernel(
    const float* __restrict__ hidden, float* __restrict__ ws0)
{
    const int blk = blockIdx.x;           // b * NCHUNK + c
    const int b   = blk / NCHUNK;
    const int c   = blk % NCHUNK;
    const int t   = threadIdx.x;          // owns cols 4t..4t+3

    const float* base = hidden + ((size_t)b * S_LEN + (size_t)c * CHUNK) * HDIM + 4 * t;
    float4 m = make_float4(-FLT_MAX, -FLT_MAX, -FLT_MAX, -FLT_MAX);
    #pragma unroll
    for (int s = 0; s < CHUNK; ++s)
        fmax4(m, *reinterpret_cast<const float4*>(base + (size_t)s * HDIM));

    *reinterpret_cast<float4*>(ws0 + ((size_t)b * NCHUNK + c) * HDIM + 4 * t) = m;
}

// ---- K2: fused pool (4 row-teams) + GEMM (16 waves).
__global__ __launch_bounds__(1024) void pool_gemm2(
    const float* __restrict__ hidden,
    const float* __restrict__ ws0,
    const float* __restrict__ W,
    const float* __restrict__ bias,
    const int*   __restrict__ cand_batch,
    const int*   __restrict__ cand_cut,
    float*       __restrict__ out)
{
    __shared__ float partL[4][HDIM];     // 16 KB
    __shared__ float partR[4][HDIM];     // 16 KB
    __shared__ float pooled[2 * HDIM];   // 8 KB
    __shared__ float gpart[16][NLAB];    // 2.2 KB

    const int n   = blockIdx.x;
    const int t   = threadIdx.x;         // 0..1023
    const int g   = t >> 8;              // row-team 0..3
    const int tt  = t & 255;             // thread-in-team -> cols 4tt..4tt+3
    const int col = 4 * tt;
    const int b   = cand_batch[n];
    const int cut = cand_cut[n];                 // block-uniform
    const int fcL = cut >> 4;                    // chunks [0,fcL) fully left
    const int fcR = (cut + CHUNK - 1) >> 4;      // chunks [fcR,32) fully right

    const float* hbase = hidden + (size_t)b * S_LEN * HDIM + col;
    const float* wbase = ws0 + (size_t)b * NCHUNK * HDIM + col;

    float4 mL = make_float4(-FLT_MAX, -FLT_MAX, -FLT_MAX, -FLT_MAX);
    float4 mR = mL;

    // full chunks, strided by team
    #pragma unroll 2
    for (int c = g; c < fcL; c += 4)
        fmax4(mL, *reinterpret_cast<const float4*>(wbase + (size_t)c * HDIM));
    const int c0 = fcR + ((g - fcR) & 3);        // smallest c>=fcR with c%4==g
    #pragma unroll 2
    for (int c = c0; c < NCHUNK; c += 4)
        fmax4(mR, *reinterpret_cast<const float4*>(wbase + (size_t)c * HDIM));

    // boundary rows, strided by team
    #pragma unroll 2
    for (int s = fcL * CHUNK + g; s < cut; s += 4)
        fmax4(mL, *reinterpret_cast<const float4*>(hbase + (size_t)s * HDIM));
    #pragma unroll 2
    for (int s = cut + g; s < fcR * CHUNK; s += 4)
        fmax4(mR, *reinterpret_cast<const float4*>(hbase + (size_t)s * HDIM));

    *reinterpret_cast<float4*>(&partL[g][col]) = mL;
    *reinterpret_cast<float4*>(&partR[g][col]) = mR;
    __syncthreads();

    // 4-way combine: thread t handles pooled cols {t, t+1024}
    {
        const int j = t;                         // 0..1023 -> left half
        pooled[j] = fmaxf(fmaxf(partL[0][j], partL[1][j]),
                          fmaxf(partL[2][j], partL[3][j]));
        pooled[HDIM + j] = fmaxf(fmaxf(partR[0][j], partR[1][j]),
                                 fmaxf(partR[2][j], partR[3][j]));
    }
    __syncthreads();

    // GEMM: wave w owns k in [128w, 128w+128); lanes 0..33 own a label.
    const int w    = t >> 6;                     // 0..15
    const int lane = t & 63;
    if (lane < NLAB) {
        const float* p = pooled + 128 * w;
        const float* Wp = W + (size_t)(128 * w) * NLAB + lane;
        float acc = 0.0f;
        #pragma unroll 8
        for (int k = 0; k < 128; ++k)
            acc = fmaf(p[k], Wp[(size_t)k * NLAB], acc);
        gpart[w][lane] = acc;
    }
    __syncthreads();

    if (t < NLAB) {
        float s = bias[t];
        #pragma unroll
        for (int w2 = 0; w2 < 16; ++w2) s += gpart[w2][t];
        out[(size_t)n * NLAB + t] = s;
    }
}

// ---- Fallback: proven single-kernel path (only if ws too small).
__global__ __launch_bounds__(256) void dmbert_pool_gemm(
    const float* __restrict__ hidden,
    const float* __restrict__ W,
    const float* __restrict__ bias,
    const int*   __restrict__ cand_batch,
    const int*   __restrict__ cand_cut,
    float*       __restrict__ out)
{
    __shared__ float pooled[2 * HDIM];
    __shared__ float partial[4][NLAB];

    const int n   = blockIdx.x;
    const int t   = threadIdx.x;
    const int bi  = cand_batch[n];
    const int cut = cand_cut[n];

    const float* base = hidden + (size_t)bi * S_LEN * HDIM + 4 * t;
    float4 mL = make_float4(-FLT_MAX, -FLT_MAX, -FLT_MAX, -FLT_MAX);
    float4 mR = mL;

    #pragma unroll 4
    for (int s = 0; s < cut; ++s)
        fmax4(mL, *reinterpret_cast<const float4*>(base + (size_t)s * HDIM));
    #pragma unroll 4
    for (int s = cut; s < S_LEN; ++s)
        fmax4(mR, *reinterpret_cast<const float4*>(base + (size_t)s * HDIM));

    *reinterpret_cast<float4*>(&pooled[4 * t])        = mL;
    *reinterpret_cast<float4*>(&pooled[HDIM + 4 * t]) = mR;
    __syncthreads();

    const int w    = t >> 6;
    const int lane = t & 63;
    if (lane < NLAB) {
        const int k0 = w * (2 * HDIM / 4);
        float acc = 0.0f;
        #pragma unroll 8
        for (int k = k0; k < k0 + (2 * HDIM / 4); ++k)
            acc = fmaf(pooled[k], W[(size_t)k * NLAB + lane], acc);
        partial[w][lane] = acc;
    }
    __syncthreads();

    if (t < NLAB) {
        out[(size_t)n * NLAB + t] =
            partial[0][t] + partial[1][t] + partial[2][t] + partial[3][t] + bias[t];
    }
}

extern "C" void kernel_launch(void* const* d_in, const int* in_sizes, int n_in,
                              void* d_out, int out_size, void* d_ws, size_t ws_size,
                              hipStream_t stream) {
    const float* hidden = (const float*)d_in[0];
    const float* W      = (const float*)d_in[1];
    const float* bias   = (const float*)d_in[2];
    const int*   cb     = (const int*)d_in[3];
    const int*   cc     = (const int*)d_in[4];
    float*       outp   = (float*)d_out;

    const int ncand = in_sizes[3];                       // 256
    const int B     = in_sizes[0] / (S_LEN * HDIM);      // 32
    const size_t ws_needed = (size_t)B * NCHUNK * HDIM * sizeof(float);  // 4 MB

    if (ws_size >= ws_needed) {
        float* cm = (float*)d_ws;
        chunkmax_kernel<<<B * NCHUNK, 256, 0, stream>>>(hidden, cm);
        pool_gemm2<<<ncand, 1024, 0, stream>>>(hidden, cm, W, bias, cb, cc, outp);
    } else {
        dmbert_pool_gemm<<<ncand, 256, 0, stream>>>(hidden, W, bias, cb, cc, outp);
    }
}